// Round 4
// baseline (261.556 us; speedup 1.0000x reference)
//
#include <hip/hip_runtime.h>
#include <hip/hip_bf16.h>

#define Bn 8
#define Nn 4096
#define Cn 1024
#define Dn 512
#define Mn 64

typedef __hip_bfloat16 bf16;
typedef __attribute__((ext_vector_type(8))) short short8;
typedef __attribute__((ext_vector_type(4))) short short4x;
typedef __attribute__((ext_vector_type(4))) float f32x4;

#define MFMA16(a, b, c) __builtin_amdgcn_mfma_f32_16x16x32_bf16((a), (b), (c), 0, 0, 0)

__device__ inline short bfbits(float f) {
  union { bf16 b; short s; } u;
  u.b = __float2bfloat16(f);
  return u.s;
}

// ---------------------------------------------------------------------------
// K0: V[m][c] = sum_d av[m][d]*W[d][c]  (bf16 hi+lo);  c0[m] = av[m,:].bias
// grid (Mn, Cn/64) = 1024 blocks, block 256  [verified]
// ---------------------------------------------------------------------------
__global__ __launch_bounds__(256) void prep_kernel(
    const float* __restrict__ W, const float* __restrict__ bias,
    const float* __restrict__ av, bf16* __restrict__ Vhi,
    bf16* __restrict__ Vlo, float* __restrict__ c0) {
  const int m = blockIdx.x;
  const int t = threadIdx.x;
  const int cl = t & 63, dg = t >> 6;
  const int c = blockIdx.y * 64 + cl;
  const float* wp = W + (size_t)(dg * 128) * Cn + c;
  const float* ap = av + m * Dn + dg * 128;
  float a0 = 0.f, a1 = 0.f, a2 = 0.f, a3 = 0.f;
#pragma unroll 8
  for (int i = 0; i < 128; i += 4) {
    a0 = fmaf(ap[i + 0], wp[(size_t)(i + 0) * Cn], a0);
    a1 = fmaf(ap[i + 1], wp[(size_t)(i + 1) * Cn], a1);
    a2 = fmaf(ap[i + 2], wp[(size_t)(i + 2) * Cn], a2);
    a3 = fmaf(ap[i + 3], wp[(size_t)(i + 3) * Cn], a3);
  }
  __shared__ float red[256];
  red[t] = (a0 + a1) + (a2 + a3);
  __syncthreads();
  const float v = red[cl] + red[cl + 64] + red[cl + 128] + red[cl + 192];
  if (dg == 0) {
    const bf16 hi = __float2bfloat16(v);
    Vhi[m * Cn + c] = hi;
    Vlo[m * Cn + c] = __float2bfloat16(v - __bfloat162float(hi));
  }
  if (blockIdx.y == 0) {
    __syncthreads();
    red[t] = av[m * Dn + t] * bias[t] + av[m * Dn + t + 256] * bias[t + 256];
    __syncthreads();
    if (t < 64) {
      float s = red[t] + red[t + 64] + red[t + 128] + red[t + 192];
#pragma unroll
      for (int off = 32; off > 0; off >>= 1) s += __shfl_down(s, off);
      if (t == 0) c0[m] = s;
    }
  }
}

// ---------------------------------------------------------------------------
// K1: logits tile (64n x 64m) + LOCAL softmax fused.
// For each m and this block's 64-n group g: Mp = local max, Sp = sum of
// e^{acc-Mp}; store UNNORMALIZED wgt = bf16(e^{acc-Mp}).  The bias c0[m]
// cancels inside e^{acc-Mp}; it is folded into the stored Mp (= max_l).
// Eliminates the fp32 logits buffer and the separate softmax kernel.
// grid (Nn/64, Bn) = 512, block 256.  [staging/MFMA body verified]
// ---------------------------------------------------------------------------
__global__ __launch_bounds__(256) void logits_sm_kernel(
    const float* __restrict__ x, const bf16* __restrict__ Vhi,
    const bf16* __restrict__ Vlo, const float* __restrict__ c0,
    bf16* __restrict__ wgt, float* __restrict__ Mp, float* __restrict__ Sp) {
  const int g = blockIdx.x;       // n-group index (64 per b)
  const int n0 = g * 64;
  const int b = blockIdx.y;
  const int t = threadIdx.x;
  __shared__ short Xs[64][136];
  __shared__ short VsH[64][136];
  __shared__ short VsL[64][136];
  const int w = t >> 6, lane = t & 63, lr = lane & 15, q = lane >> 4;
  const ptrdiff_t dlo = Vlo - Vhi;

  int ur[4], uc[4];
  const float* xsrc[4];
  const bf16* hsrc[4];
#pragma unroll
  for (int j = 0; j < 4; ++j) {
    const int u = t + 256 * j;
    ur[j] = u >> 4;
    uc[j] = (u & 15) * 8;
    xsrc[j] = x + (size_t)(b * Nn + n0 + ur[j]) * Cn + uc[j];
    hsrc[j] = Vhi + ur[j] * Cn + uc[j];
  }

  f32x4 acc[4];
#pragma unroll
  for (int i = 0; i < 4; ++i) acc[i] = (f32x4){0.f, 0.f, 0.f, 0.f};

  float4 px0[4], px1[4];
  short8 pvh[4], pvl[4];
#pragma unroll
  for (int j = 0; j < 4; ++j) {
    px0[j] = *(const float4*)(xsrc[j]);
    px1[j] = *(const float4*)(xsrc[j] + 4);
    pvh[j] = *(const short8*)(hsrc[j]);
    pvl[j] = *(const short8*)(hsrc[j] + dlo);
  }

  for (int k0 = 0; k0 < Cn; k0 += 128) {
#pragma unroll
    for (int j = 0; j < 4; ++j) {
      short8 s;
      s[0] = bfbits(px0[j].x); s[1] = bfbits(px0[j].y);
      s[2] = bfbits(px0[j].z); s[3] = bfbits(px0[j].w);
      s[4] = bfbits(px1[j].x); s[5] = bfbits(px1[j].y);
      s[6] = bfbits(px1[j].z); s[7] = bfbits(px1[j].w);
      *(short8*)&Xs[ur[j]][uc[j]] = s;
      *(short8*)&VsH[ur[j]][uc[j]] = pvh[j];
      *(short8*)&VsL[ur[j]][uc[j]] = pvl[j];
    }
    __syncthreads();
    if (k0 + 128 < Cn) {
#pragma unroll
      for (int j = 0; j < 4; ++j) {
        px0[j] = *(const float4*)(xsrc[j] + k0 + 128);
        px1[j] = *(const float4*)(xsrc[j] + k0 + 132);
        pvh[j] = *(const short8*)(hsrc[j] + k0 + 128);
        pvl[j] = *(const short8*)(hsrc[j] + dlo + k0 + 128);
      }
    }
#pragma unroll
    for (int kk = 0; kk < 128; kk += 32) {
      const short8 a = *(const short8*)&Xs[w * 16 + lr][kk + q * 8];
#pragma unroll
      for (int mt = 0; mt < 4; ++mt) {
        acc[mt] = MFMA16(a, *(const short8*)&VsH[mt * 16 + lr][kk + q * 8], acc[mt]);
        acc[mt] = MFMA16(a, *(const short8*)&VsL[mt * 16 + lr][kk + q * 8], acc[mt]);
      }
    }
    __syncthreads();
  }

  // ---- local softmax epilogue (D layout: row n=q*4+reg, col m=lr) ----
  float* wredM = (float*)&Xs[0][0];   // [4][64]  (Xs dead after last sync)
  float* wredS = wredM + 256;         // [4][64]
  float rmax[4];
#pragma unroll
  for (int mt = 0; mt < 4; ++mt) {
    float r = fmaxf(fmaxf(acc[mt][0], acc[mt][1]), fmaxf(acc[mt][2], acc[mt][3]));
    r = fmaxf(r, __shfl_xor(r, 16));
    r = fmaxf(r, __shfl_xor(r, 32));
    rmax[mt] = r;   // warp-local max over its 16 n, for m = mt*16+lr
  }
  if (q == 0)
#pragma unroll
    for (int mt = 0; mt < 4; ++mt) wredM[w * 64 + mt * 16 + lr] = rmax[mt];
  __syncthreads();
  float vv[4][4];
#pragma unroll
  for (int mt = 0; mt < 4; ++mt) {
    const int m = mt * 16 + lr;
    const float mp = fmaxf(fmaxf(wredM[m], wredM[64 + m]),
                           fmaxf(wredM[128 + m], wredM[192 + m]));
    float s = 0.f;
#pragma unroll
    for (int r = 0; r < 4; ++r) {
      vv[mt][r] = __expf(acc[mt][r] - mp);
      s += vv[mt][r];
    }
    s += __shfl_xor(s, 16);
    s += __shfl_xor(s, 32);
    if (q == 0) wredS[w * 64 + m] = s;
  }
  // unnormalized weights out (no cross-warp data needed)
#pragma unroll
  for (int mt = 0; mt < 4; ++mt) {
    const int m = mt * 16 + lr;
    short4x o;
    o[0] = bfbits(vv[mt][0]); o[1] = bfbits(vv[mt][1]);
    o[2] = bfbits(vv[mt][2]); o[3] = bfbits(vv[mt][3]);
    *(short4x*)&wgt[(size_t)(b * Mn + m) * Nn + n0 + w * 16 + q * 4] = o;
  }
  __syncthreads();
  if (w == 0) {  // lane = m
    const int m = lane;
    const float mp = fmaxf(fmaxf(wredM[m], wredM[64 + m]),
                           fmaxf(wredM[128 + m], wredM[192 + m]));
    const float sp = wredS[m] + wredS[64 + m] + wredS[128 + m] + wredS[192 + m];
    Mp[((size_t)b * Mn + m) * 64 + g] = mp + c0[m];  // fold bias into stored max
    Sp[((size_t)b * Mn + m) * 64 + g] = sp;
  }
}

// ---------------------------------------------------------------------------
// K2: part[ks][b][m][c] = sum_{g in quarter} s(m,g) * sum_{n in g} wgt[n]*x[n][c]
// Prologue: global M,S per m from Mp/Sp (L2-hot, 32KB), scale table
// scs[g][m] = e^{Mp-M}/S in LDS.  Main loop accumulates per-64-k-group into
// accg and folds accT += scs*accg at (compile-time) group boundaries.
// Staging/swizzle identical to verified pool.  grid (Cn/64, Bn, 4), block 256.
// ---------------------------------------------------------------------------
__global__ __launch_bounds__(256) void pool_kernel(
    const float* __restrict__ x, const bf16* __restrict__ wgt,
    const float* __restrict__ Mp, const float* __restrict__ Sp,
    float* __restrict__ part) {
  const int cbase = blockIdx.x * 64;
  const int b = blockIdx.y;
  const int ks = blockIdx.z;
  const int t = threadIdx.x;
  __shared__ short XT[64][136];   // [c][k-swizzled]
  __shared__ float scs[16][64];   // [local k-group][m]
  const int w = t >> 6, lane = t & 63, lr = lane & 15, q = lane >> 4;
  const int mh = (w & 1) * 32, ch = (w >> 1) * 32;

  // ---- prologue: per-m global max/sum -> scale table for this quarter ----
  {
    const int m = t >> 2, qq = t & 3;
    const float* mpp = Mp + ((size_t)b * Mn + m) * 64 + qq * 16;
    const float* spp = Sp + ((size_t)b * Mn + m) * 64 + qq * 16;
    float mpl[16], spl[16];
#pragma unroll
    for (int j = 0; j < 16; ++j) { mpl[j] = mpp[j]; spl[j] = spp[j]; }
    float lmax = -3.4e38f;
#pragma unroll
    for (int j = 0; j < 16; ++j) lmax = fmaxf(lmax, mpl[j]);
    float gmax = fmaxf(lmax, __shfl_xor(lmax, 1));
    gmax = fmaxf(gmax, __shfl_xor(gmax, 2));
    float lsum = 0.f;
#pragma unroll
    for (int j = 0; j < 16; ++j) lsum += __expf(mpl[j] - gmax) * spl[j];
    float gsum = lsum + __shfl_xor(lsum, 1);
    gsum = gsum + __shfl_xor(gsum, 2);
    if (qq == ks) {
      const float inv = 1.f / gsum;
#pragma unroll
      for (int j = 0; j < 16; ++j) scs[j][m] = __expf(mpl[j] - gmax) * inv;
    }
  }
  __syncthreads();

  f32x4 accT[2][2], accg[2][2];
#pragma unroll
  for (int i = 0; i < 2; ++i)
#pragma unroll
    for (int j = 0; j < 2; ++j) {
      accT[i][j] = (f32x4){0.f, 0.f, 0.f, 0.f};
      accg[i][j] = (f32x4){0.f, 0.f, 0.f, 0.f};
    }

  const int h = t & 15, g = t >> 4;
  const int swz = 8 * (h & 7);
  const int swzr0 = 8 * (((ch + lr) >> 2) & 7);
  const int swzr1 = 8 * (((ch + 16 + lr) >> 2) & 7);
  const int NQ = Nn / 4;
  const int kbase = ks * NQ;
  const float* xsrc = x + (size_t)b * Nn * Cn + (size_t)(kbase + 4 * g) * Cn + cbase + 4 * h;
  const bf16* wr0 = wgt + (size_t)(b * Mn + mh + lr) * Nn + kbase;
  const bf16* wr1 = wr0 + (size_t)16 * Nn;

  float4 pf[8];
#pragma unroll
  for (int i = 0; i < 4; ++i) {
    pf[i]     = *(const float4*)(xsrc + (size_t)i * Cn);
    pf[4 + i] = *(const float4*)(xsrc + (size_t)(64 + i) * Cn);
  }

  for (int kc = 0; kc < NQ; kc += 128) {
#pragma unroll
    for (int blk = 0; blk < 2; ++blk) {
      const float4 r0 = pf[blk * 4 + 0], r1 = pf[blk * 4 + 1];
      const float4 r2 = pf[blk * 4 + 2], r3 = pf[blk * 4 + 3];
      const int kof = (blk * 64 + 4 * g) ^ swz;
      short4x v0, v1, v2, v3;
      v0[0] = bfbits(r0.x); v0[1] = bfbits(r1.x); v0[2] = bfbits(r2.x); v0[3] = bfbits(r3.x);
      v1[0] = bfbits(r0.y); v1[1] = bfbits(r1.y); v1[2] = bfbits(r2.y); v1[3] = bfbits(r3.y);
      v2[0] = bfbits(r0.z); v2[1] = bfbits(r1.z); v2[2] = bfbits(r2.z); v2[3] = bfbits(r3.z);
      v3[0] = bfbits(r0.w); v3[1] = bfbits(r1.w); v3[2] = bfbits(r2.w); v3[3] = bfbits(r3.w);
      *(short4x*)&XT[4 * h + 0][kof] = v0;
      *(short4x*)&XT[4 * h + 1][kof] = v1;
      *(short4x*)&XT[4 * h + 2][kof] = v2;
      *(short4x*)&XT[4 * h + 3][kof] = v3;
    }
    __syncthreads();
    if (kc + 128 < NQ) {
#pragma unroll
      for (int i = 0; i < 4; ++i) {
        pf[i]     = *(const float4*)(xsrc + (size_t)(kc + 128 + i) * Cn);
        pf[4 + i] = *(const float4*)(xsrc + (size_t)(kc + 192 + i) * Cn);
      }
    }
#pragma unroll
    for (int kk = 0; kk < 128; kk += 32) {
      const short8 a0 = *(const short8*)(wr0 + kc + kk + q * 8);
      const short8 a1 = *(const short8*)(wr1 + kc + kk + q * 8);
      const short8 b0 = *(const short8*)&XT[ch + lr][(kk + q * 8) ^ swzr0];
      const short8 b1 = *(const short8*)&XT[ch + 16 + lr][(kk + q * 8) ^ swzr1];
      accg[0][0] = MFMA16(a0, b0, accg[0][0]);
      accg[0][1] = MFMA16(a0, b1, accg[0][1]);
      accg[1][0] = MFMA16(a1, b0, accg[1][0]);
      accg[1][1] = MFMA16(a1, b1, accg[1][1]);
      if (kk == 32 || kk == 96) {  // 64-k group boundary (compile-time)
        const int gl = (kc + kk) >> 6;  // local group 0..15
#pragma unroll
        for (int mi = 0; mi < 2; ++mi)
#pragma unroll
          for (int r = 0; r < 4; ++r) {
            const float s = scs[gl][mh + mi * 16 + q * 4 + r];
            accT[mi][0][r] = fmaf(s, accg[mi][0][r], accT[mi][0][r]);
            accT[mi][1][r] = fmaf(s, accg[mi][1][r], accT[mi][1][r]);
            accg[mi][0][r] = 0.f;
            accg[mi][1][r] = 0.f;
          }
      }
    }
    __syncthreads();
  }
  float* pout = part + ((size_t)ks * Bn + b) * Mn * Cn;
#pragma unroll
  for (int mi = 0; mi < 2; ++mi)
#pragma unroll
    for (int ci = 0; ci < 2; ++ci) {
      const int m = mh + mi * 16 + q * 4;
      const int c = cbase + ch + ci * 16 + lr;
#pragma unroll
      for (int reg = 0; reg < 4; ++reg)
        pout[(size_t)(m + reg) * Cn + c] = accT[mi][ci][reg];
    }
}

// ---------------------------------------------------------------------------
// K3: out = sum of 4 partials (float4).  grid 512, block 256
// ---------------------------------------------------------------------------
__global__ __launch_bounds__(256) void reduce_kernel(
    const float* __restrict__ part, float* __restrict__ out) {
  const int i = blockIdx.x * 256 + threadIdx.x;
  const float4* p = (const float4*)part;
  const int S4 = (Bn * Mn * Cn) / 4;
  const float4 v0 = p[i], v1 = p[i + S4], v2 = p[i + 2 * S4], v3 = p[i + 3 * S4];
  float4 o;
  o.x = (v0.x + v1.x) + (v2.x + v3.x);
  o.y = (v0.y + v1.y) + (v2.y + v3.y);
  o.z = (v0.z + v1.z) + (v2.z + v3.z);
  o.w = (v0.w + v1.w) + (v2.w + v3.w);
  ((float4*)out)[i] = o;
}

extern "C" void kernel_launch(void* const* d_in, const int* in_sizes, int n_in,
                              void* d_out, int out_size, void* d_ws, size_t ws_size,
                              hipStream_t stream) {
  const float* x = (const float*)d_in[0];
  const float* W = (const float*)d_in[1];
  const float* bias = (const float*)d_in[2];
  const float* av = (const float*)d_in[3];
  float* out = (float*)d_out;
  char* ws = (char*)d_ws;

  bf16* Vhi = (bf16*)(ws + 0);           // 131072 B
  bf16* Vlo = (bf16*)(ws + 131072);      // 131072 B
  float* c0 = (float*)(ws + 262144);     // 1024 B
  bf16* wgt = (bf16*)(ws + 263168);      // 4194304 B
  float* Mp = (float*)(ws + 4457472);    // 131072 B
  float* Sp = (float*)(ws + 4588544);    // 131072 B
  float* part = (float*)(ws + 4719616);  // 8388608 B  (total ~13.1 MB)

  prep_kernel<<<dim3(Mn, Cn / 64), 256, 0, stream>>>(W, bias, av, Vhi, Vlo, c0);
  logits_sm_kernel<<<dim3(Nn / 64, Bn), 256, 0, stream>>>(x, Vhi, Vlo, c0, wgt, Mp, Sp);
  pool_kernel<<<dim3(Cn / 64, Bn, 4), 256, 0, stream>>>(x, wgt, Mp, Sp, part);
  reduce_kernel<<<(Bn * Mn * Cn) / 1024, 256, 0, stream>>>(part, out);
}